// Round 1
// baseline (180.312 us; speedup 1.0000x reference)
//
#include <hip/hip_runtime.h>

typedef __bf16 bf16x8 __attribute__((ext_vector_type(8)));
typedef float f32x4 __attribute__((ext_vector_type(4)));
typedef unsigned short ushort8 __attribute__((ext_vector_type(8)));

// float -> bf16, round-to-nearest-even, bit-level (deterministic, no type friction)
__device__ __forceinline__ unsigned short f2bf(float f) {
  unsigned int u = __float_as_uint(f);
  u += 0x7FFFu + ((u >> 16) & 1u);
  return (unsigned short)(u >> 16);
}

// fake-quant one value: clip -> round((t-lb)/delta) -> k*delta+lb, then bf16
__device__ __forceinline__ unsigned short quant1(float v, float lb, float ub, float delta) {
  float t = fminf(fmaxf(v, lb), ub);
  float k = rintf((t - lb) / delta);
  return f2bf(k * delta + lb);
}

__global__ void quant_x_kernel(const float* __restrict__ x, unsigned short* __restrict__ qx,
                               const float* __restrict__ lbp, const float* __restrict__ ubp,
                               int ngroups) {
  const float lb = lbp[0], ub = ubp[0];
  const float delta = (ub - lb) / 15.0f;
  for (int i = blockIdx.x * blockDim.x + threadIdx.x; i < ngroups;
       i += gridDim.x * blockDim.x) {
    const float4* p = reinterpret_cast<const float4*>(x) + (size_t)i * 2;
    float4 v0 = p[0], v1 = p[1];
    ushort8 o;
    o[0] = quant1(v0.x, lb, ub, delta);
    o[1] = quant1(v0.y, lb, ub, delta);
    o[2] = quant1(v0.z, lb, ub, delta);
    o[3] = quant1(v0.w, lb, ub, delta);
    o[4] = quant1(v1.x, lb, ub, delta);
    o[5] = quant1(v1.y, lb, ub, delta);
    o[6] = quant1(v1.z, lb, ub, delta);
    o[7] = quant1(v1.w, lb, ub, delta);
    *reinterpret_cast<ushort8*>(qx + (size_t)i * 8) = o;
  }
}

__global__ void quant_w_kernel(const float* __restrict__ w, unsigned short* __restrict__ qw,
                               const float* __restrict__ lbp, const float* __restrict__ ubp,
                               int ngroups, int groups_per_row) {
  for (int i = blockIdx.x * blockDim.x + threadIdx.x; i < ngroups;
       i += gridDim.x * blockDim.x) {
    const int row = i / groups_per_row;
    const float lb = lbp[row], ub = ubp[row];
    const float delta = (ub - lb) / 15.0f;
    const float4* p = reinterpret_cast<const float4*>(w) + (size_t)i * 2;
    float4 v0 = p[0], v1 = p[1];
    ushort8 o;
    o[0] = quant1(v0.x, lb, ub, delta);
    o[1] = quant1(v0.y, lb, ub, delta);
    o[2] = quant1(v0.z, lb, ub, delta);
    o[3] = quant1(v0.w, lb, ub, delta);
    o[4] = quant1(v1.x, lb, ub, delta);
    o[5] = quant1(v1.y, lb, ub, delta);
    o[6] = quant1(v1.z, lb, ub, delta);
    o[7] = quant1(v1.w, lb, ub, delta);
    *reinterpret_cast<ushort8*>(qw + (size_t)i * 8) = o;
  }
}

__device__ __forceinline__ void gload_lds16(const void* g, void* l) {
  __builtin_amdgcn_global_load_lds(
      (const __attribute__((address_space(1))) unsigned int*)g,
      (__attribute__((address_space(3))) unsigned int*)l, 16, 0, 0);
}

#define BM 128
#define BN 128
#define BK 32

// C[M][N] = A[M][K] * B[N][K]^T + bias ; A,B bf16 (as ushort), C fp32
__global__ __launch_bounds__(256) void gemm_bt_kernel(
    const unsigned short* __restrict__ A, const unsigned short* __restrict__ B,
    const float* __restrict__ bias, float* __restrict__ C,
    int M, int N, int K) {
  __shared__ unsigned short As[BM * BK];  // 8 KB, row-major [row][k]
  __shared__ unsigned short Bs[BN * BK];  // 8 KB, row-major [nrow][k]

  const int tid = threadIdx.x;
  const int w = tid >> 6;
  const int l = tid & 63;
  const int wr = w >> 1, wc = w & 1;

  // XCD-aware bijective swizzle (grid % 8 == 0 here)
  int bid = blockIdx.x;
  const int nwg = gridDim.x;
  if ((nwg & 7) == 0) {
    const int cpx = nwg >> 3;
    bid = (bid & 7) * cpx + (bid >> 3);
  }
  const int ntn = N / BN;
  const int tm = bid / ntn, tn = bid % ntn;

  const unsigned short* gA = A + (size_t)tm * BM * K;
  const unsigned short* gB = B + (size_t)tn * BN * K;

  // staging: 4 waves x 2 chunks x 1KB per matrix; lane l -> chunk_base + l*16B
  const int rl = l >> 2;        // row within 16-row chunk
  const int ce = (l & 3) * 8;   // element offset within 32-elem row
  const unsigned short* gA0 = gA + (size_t)((w * 2 + 0) * 16 + rl) * K + ce;
  const unsigned short* gA1 = gA + (size_t)((w * 2 + 1) * 16 + rl) * K + ce;
  const unsigned short* gB0 = gB + (size_t)((w * 2 + 0) * 16 + rl) * K + ce;
  const unsigned short* gB1 = gB + (size_t)((w * 2 + 1) * 16 + rl) * K + ce;
  unsigned short* lA0 = &As[(w * 2 + 0) * 512];  // wave-uniform LDS bases
  unsigned short* lA1 = &As[(w * 2 + 1) * 512];
  unsigned short* lB0 = &Bs[(w * 2 + 0) * 512];
  unsigned short* lB1 = &Bs[(w * 2 + 1) * 512];

  // fragment read offsets (A row = wr*64+fr, k = (l>>4)*8)
  const int fr = l & 15;
  const int kq = (l >> 4) * 8;
  const int offA = (wr * 64 + fr) * BK + kq;
  const int offB = (wc * 64 + fr) * BK + kq;

  f32x4 acc[4][4] = {};

  const int nkt = K / BK;
  for (int kt = 0; kt < nkt; ++kt) {
    const int ko = kt * BK;
    gload_lds16(gA0 + ko, lA0);
    gload_lds16(gA1 + ko, lA1);
    gload_lds16(gB0 + ko, lB0);
    gload_lds16(gB1 + ko, lB1);
    __syncthreads();  // drains vmcnt (global_load_lds) before reads

    bf16x8 av[4], bv[4];
#pragma unroll
    for (int m = 0; m < 4; ++m)
      av[m] = *reinterpret_cast<const bf16x8*>(&As[offA + m * 16 * BK]);
#pragma unroll
    for (int n = 0; n < 4; ++n)
      bv[n] = *reinterpret_cast<const bf16x8*>(&Bs[offB + n * 16 * BK]);
#pragma unroll
    for (int m = 0; m < 4; ++m)
#pragma unroll
      for (int n = 0; n < 4; ++n)
        acc[m][n] = __builtin_amdgcn_mfma_f32_16x16x32_bf16(av[m], bv[n], acc[m][n], 0, 0, 0);
    __syncthreads();  // protect LDS from next iteration's staging
  }

  // epilogue: C/D layout col=lane&15, row=(lane>>4)*4+reg  [m89-verified]
  const int rquad = (l >> 4) * 4;
  const int cn = l & 15;
  const int mb = tm * BM + wr * 64;
  const int nb = tn * BN + wc * 64;
#pragma unroll
  for (int n = 0; n < 4; ++n) {
    const int col = nb + n * 16 + cn;
    const float bs = bias[col];
#pragma unroll
    for (int m = 0; m < 4; ++m) {
      float* cp = C + (size_t)(mb + m * 16 + rquad) * N + col;
      cp[0] = acc[m][n][0] + bs;
      cp[(size_t)N] = acc[m][n][1] + bs;
      cp[(size_t)2 * N] = acc[m][n][2] + bs;
      cp[(size_t)3 * N] = acc[m][n][3] + bs;
    }
  }
}

extern "C" void kernel_launch(void* const* d_in, const int* in_sizes, int n_in,
                              void* d_out, int out_size, void* d_ws, size_t ws_size,
                              hipStream_t stream) {
  const float* x     = (const float*)d_in[0];
  const float* wgt   = (const float*)d_in[1];
  const float* bias  = (const float*)d_in[2];
  const float* in_lb = (const float*)d_in[3];
  const float* in_ub = (const float*)d_in[4];
  const float* w_lb  = (const float*)d_in[5];
  const float* w_ub  = (const float*)d_in[6];

  const int Dout = in_sizes[2];            // 3072
  const int Din  = in_sizes[1] / Dout;     // 1024
  const int M    = in_sizes[0] / Din;      // 16384 (B*S)

  unsigned short* qx = (unsigned short*)d_ws;                  // M*Din bf16
  unsigned short* qw = qx + (size_t)M * Din;                   // Dout*Din bf16

  const int ngx = (M * Din) / 8;
  quant_x_kernel<<<2048, 256, 0, stream>>>(x, qx, in_lb, in_ub, ngx);

  const int ngw = (Dout * Din) / 8;
  quant_w_kernel<<<1536, 256, 0, stream>>>(wgt, qw, w_lb, w_ub, ngw, Din / 8);

  dim3 grid((M / BM) * (Dout / BN));
  gemm_bt_kernel<<<grid, 256, 0, stream>>>(qx, qw, bias, (float*)d_out, M, Dout, Din);
}

// Round 2
// 145.661 us; speedup vs baseline: 1.2379x; 1.2379x over previous
//
#include <hip/hip_runtime.h>

typedef __bf16 bf16x8 __attribute__((ext_vector_type(8)));
typedef float f32x4 __attribute__((ext_vector_type(4)));
typedef unsigned short ushort8 __attribute__((ext_vector_type(8)));

// float -> bf16, round-to-nearest-even
__device__ __forceinline__ unsigned short f2bf(float f) {
  unsigned int u = __float_as_uint(f);
  u += 0x7FFFu + ((u >> 16) & 1u);
  return (unsigned short)(u >> 16);
}

__device__ __forceinline__ unsigned short quant1(float v, float lb, float ub, float delta) {
  float t = fminf(fmaxf(v, lb), ub);
  float k = rintf((t - lb) / delta);
  return f2bf(k * delta + lb);
}

__global__ void quant_x_kernel(const float* __restrict__ x, unsigned short* __restrict__ qx,
                               const float* __restrict__ lbp, const float* __restrict__ ubp,
                               int ngroups) {
  const float lb = lbp[0], ub = ubp[0];
  const float delta = (ub - lb) / 15.0f;
  for (int i = blockIdx.x * blockDim.x + threadIdx.x; i < ngroups;
       i += gridDim.x * blockDim.x) {
    const float4* p = reinterpret_cast<const float4*>(x) + (size_t)i * 2;
    float4 v0 = p[0], v1 = p[1];
    ushort8 o;
    o[0] = quant1(v0.x, lb, ub, delta); o[1] = quant1(v0.y, lb, ub, delta);
    o[2] = quant1(v0.z, lb, ub, delta); o[3] = quant1(v0.w, lb, ub, delta);
    o[4] = quant1(v1.x, lb, ub, delta); o[5] = quant1(v1.y, lb, ub, delta);
    o[6] = quant1(v1.z, lb, ub, delta); o[7] = quant1(v1.w, lb, ub, delta);
    *reinterpret_cast<ushort8*>(qx + (size_t)i * 8) = o;
  }
}

__global__ void quant_w_kernel(const float* __restrict__ w, unsigned short* __restrict__ qw,
                               const float* __restrict__ lbp, const float* __restrict__ ubp,
                               int ngroups, int groups_per_row) {
  for (int i = blockIdx.x * blockDim.x + threadIdx.x; i < ngroups;
       i += gridDim.x * blockDim.x) {
    const int row = i / groups_per_row;
    const float lb = lbp[row], ub = ubp[row];
    const float delta = (ub - lb) / 15.0f;
    const float4* p = reinterpret_cast<const float4*>(w) + (size_t)i * 2;
    float4 v0 = p[0], v1 = p[1];
    ushort8 o;
    o[0] = quant1(v0.x, lb, ub, delta); o[1] = quant1(v0.y, lb, ub, delta);
    o[2] = quant1(v0.z, lb, ub, delta); o[3] = quant1(v0.w, lb, ub, delta);
    o[4] = quant1(v1.x, lb, ub, delta); o[5] = quant1(v1.y, lb, ub, delta);
    o[6] = quant1(v1.z, lb, ub, delta); o[7] = quant1(v1.w, lb, ub, delta);
    *reinterpret_cast<ushort8*>(qw + (size_t)i * 8) = o;
  }
}

__device__ __forceinline__ void gload_lds16(const unsigned short* g, unsigned short* l) {
  __builtin_amdgcn_global_load_lds(
      (const __attribute__((address_space(1))) unsigned int*)g,
      (__attribute__((address_space(3))) unsigned int*)l, 16, 0, 0);
}

// involution swizzle: XOR kbyte bits 4-5 with row bits 1-2 (o bits 7-8).
// Applied to BOTH the staging source (pre-swizzled global addr, linear LDS
// write via global_load_lds) and the ds_read address. 16-lane fragment read
// groups then cover all 8 bank-groups (2 lanes each -> conflict-free).
#define SWZ(o) ((o) ^ ((((o) >> 7) & 3) << 4))

// 256x256 tile, BK=64, 8 waves (2Mx4N), per-wave 128x64 output.
// LDS: [E/O tile buf][A/B][k-half][256 rows x 32 elems] = 128 KiB.
__global__ __launch_bounds__(512, 2) void gemm256_kernel(
    const unsigned short* __restrict__ A, const unsigned short* __restrict__ B,
    const float* __restrict__ bias, float* __restrict__ C,
    int M, int N, int K) {
  __shared__ unsigned short lds[2][2][2][8192];

  const int tid = threadIdx.x;
  const int w = tid >> 6, l = tid & 63;
  const int wm = w >> 2, wn = w & 3;

  int bid = blockIdx.x;
  { const int cpx = gridDim.x >> 3; bid = (bid & 7) * cpx + (bid >> 3); }  // grid%8==0
  const int ntn = N >> 8;
  const int tm = bid / ntn, tn = bid % ntn;

  const unsigned short* gA = A + (size_t)tm * 256 * K;
  const unsigned short* gB = B + (size_t)tn * 256 * K;

  // staging geometry: thread covers physical 16B units p0,p1 of each 16KB region
  const int p0 = tid * 16, p1 = 8192 + tid * 16;
  const int o0 = SWZ(p0), o1 = SWZ(p1);      // logical (row, kbyte)
  const int r0 = o0 >> 6, kb0 = o0 & 63;
  const int r1 = o1 >> 6, kb1 = o1 & 63;
  const unsigned short* sA0 = gA + (size_t)r0 * K + (kb0 >> 1);
  const unsigned short* sA1 = gA + (size_t)r1 * K + (kb1 >> 1);
  const unsigned short* sB0 = gB + (size_t)r0 * K + (kb0 >> 1);
  const unsigned short* sB1 = gB + (size_t)r1 * K + (kb1 >> 1);
  const int d0 = p0 >> 1, d1 = p1 >> 1;      // LDS ushort offsets (linear)

  // fragment ds_read offset: row=(base+f*16+(l&15)), kbyte=(l>>4)*16, swizzled.
  // swizzle XOR value depends only on row bits 1-2 = (l>>1)&3 -> per-thread const.
  const int lroff = (l & 15) * 64 + (((l >> 4) * 16) ^ (((l >> 1) & 3) << 4));

#define STAGE(SB, SM, SK, KOFF) do {                                     \
    unsigned short* Rb_ = &lds[SB][SM][SK][0];                           \
    gload_lds16(((SM) == 0 ? sA0 : sB0) + (KOFF), Rb_ + d0);             \
    gload_lds16(((SM) == 0 ? sA1 : sB1) + (KOFF), Rb_ + d1);             \
  } while (0)

#define RD_A(RB, KH, F) (*(const bf16x8*)((const char*)&lds[RB][0][KH][0] + wm * 8192 + (F) * 1024 + lroff))
#define RD_B(RB, KH, NN) (*(const bf16x8*)((const char*)&lds[RB][1][KH][0] + wn * 4096 + (NN) * 1024 + lroff))

#define BAR __builtin_amdgcn_s_barrier()
#define LGKM0 do { asm volatile("s_waitcnt lgkmcnt(0)" ::: "memory");    \
                   __builtin_amdgcn_sched_barrier(0); } while (0)
#define VMC4 asm volatile("s_waitcnt vmcnt(4)" ::: "memory")

  f32x4 acc[8][4] = {};
  bf16x8 av[4], bv[4];

#define MFMA16(MH) do {                                                  \
    __builtin_amdgcn_s_setprio(1);                                       \
    _Pragma("unroll") for (int mm = 0; mm < 4; ++mm)                     \
      _Pragma("unroll") for (int nn = 0; nn < 4; ++nn)                   \
        acc[(MH) * 4 + mm][nn] = __builtin_amdgcn_mfma_f32_16x16x32_bf16(\
            av[mm], bv[nn], acc[(MH) * 4 + mm][nn], 0, 0, 0);            \
    __builtin_amdgcn_s_setprio(0);                                       \
  } while (0)

// phase with fresh A(m-half0)+B reads (8 ds_read_b128), then 16 MFMA
#define PHASE_AB(RB, KS, SB, SM, SK, KOFF, VM) do {                      \
    _Pragma("unroll") for (int f = 0; f < 4; ++f) av[f] = RD_A(RB, KS, f); \
    _Pragma("unroll") for (int nn = 0; nn < 4; ++nn) bv[nn] = RD_B(RB, KS, nn); \
    STAGE(SB, SM, SK, KOFF);                                             \
    if (VM) VMC4;                                                        \
    BAR; LGKM0; MFMA16(0); BAR;                                          \
  } while (0)

// phase reusing B regs, fresh A(m-half1) reads (4 ds_read_b128)
#define PHASE_A(RB, KS, SB, SM, SK, KOFF, VM) do {                       \
    _Pragma("unroll") for (int f = 0; f < 4; ++f) av[f] = RD_A(RB, KS, 4 + f); \
    STAGE(SB, SM, SK, KOFF);                                             \
    if (VM) VMC4;                                                        \
    BAR; LGKM0; MFMA16(1); BAR;                                          \
  } while (0)

  // prologue: tile0 -> E (all 4 half-regions), tile1 k-half0 -> O
  STAGE(0, 0, 0, 0);   // E.A0
  STAGE(0, 1, 0, 0);   // E.B0
  STAGE(0, 0, 1, 32);  // E.A1
  STAGE(0, 1, 1, 32);  // E.B1
  STAGE(1, 0, 0, 64);  // O.A0 (tile1 kh0)
  STAGE(1, 1, 0, 64);  // O.B0
  VMC4; BAR;           // tile0 confirmed; 4 loads (O.A0,O.B0) in flight

  const int nkt = K >> 6;
  for (int t = 0; t < nkt; t += 2) {
    const int k1 = (t + 1) << 6;
    const int k2 = (t + 2 < nkt ? (t + 2) : 0) << 6;  // clamped: lands in dead region
    const int k3 = (t + 3 < nkt ? (t + 3) : 0) << 6;
    PHASE_AB(0, 0, 1, 0, 1, k1 + 32, 0);  // P1: E ks0 mh0 | stage O.A1 <- (t+1) kh1
    PHASE_A (0, 0, 1, 1, 1, k1 + 32, 0);  // P2: E ks0 mh1 | stage O.B1
    PHASE_AB(0, 1, 0, 0, 0, k2,      0);  // P3: E ks1 mh0 | stage E.A0 <- (t+2) kh0
    PHASE_A (0, 1, 0, 1, 0, k2,      1);  // P4: E ks1 mh1 | stage E.B0 | vmcnt(4): t+1 landed
    PHASE_AB(1, 0, 0, 0, 1, k2 + 32, 0);  // P5: O ks0 mh0 | stage E.A1 <- (t+2) kh1
    PHASE_A (1, 0, 0, 1, 1, k2 + 32, 0);  // P6: O ks0 mh1 | stage E.B1
    PHASE_AB(1, 1, 1, 0, 0, k3,      0);  // P7: O ks1 mh0 | stage O.A0 <- (t+3) kh0
    PHASE_A (1, 1, 1, 1, 0, k3,      1);  // P8: O ks1 mh1 | stage O.B0 | vmcnt(4): t+2 landed
  }

  // epilogue: C/D layout col=lane&15, row=(lane>>4)*4+reg [m89-verified]
  const int rq = (l >> 4) * 4;
  const int cn = l & 15;
  const int mb = tm * 256 + wm * 128;
  const int nb = tn * 256 + wn * 64;
#pragma unroll
  for (int n = 0; n < 4; ++n) {
    const int col = nb + n * 16 + cn;
    const float bs = bias[col];
#pragma unroll
    for (int m = 0; m < 8; ++m) {
      float* cp = C + (size_t)(mb + m * 16 + rq) * N + col;
      cp[0] = acc[m][n][0] + bs;
      cp[(size_t)N] = acc[m][n][1] + bs;
      cp[(size_t)2 * N] = acc[m][n][2] + bs;
      cp[(size_t)3 * N] = acc[m][n][3] + bs;
    }
  }
#undef STAGE
#undef RD_A
#undef RD_B
#undef BAR
#undef LGKM0
#undef VMC4
#undef MFMA16
#undef PHASE_AB
#undef PHASE_A
}

extern "C" void kernel_launch(void* const* d_in, const int* in_sizes, int n_in,
                              void* d_out, int out_size, void* d_ws, size_t ws_size,
                              hipStream_t stream) {
  const float* x     = (const float*)d_in[0];
  const float* wgt   = (const float*)d_in[1];
  const float* bias  = (const float*)d_in[2];
  const float* in_lb = (const float*)d_in[3];
  const float* in_ub = (const float*)d_in[4];
  const float* w_lb  = (const float*)d_in[5];
  const float* w_ub  = (const float*)d_in[6];

  const int Dout = in_sizes[2];            // 3072
  const int Din  = in_sizes[1] / Dout;     // 1024
  const int M    = in_sizes[0] / Din;      // 16384 (B*S)

  unsigned short* qx = (unsigned short*)d_ws;
  unsigned short* qw = qx + (size_t)M * Din;

  const int ngx = (M * Din) / 8;
  quant_x_kernel<<<2048, 256, 0, stream>>>(x, qx, in_lb, in_ub, ngx);

  const int ngw = (Dout * Din) / 8;
  quant_w_kernel<<<1536, 256, 0, stream>>>(wgt, qw, w_lb, w_ub, ngw, Din / 8);

  dim3 grid((M / 256) * (Dout / 256));
  gemm256_kernel<<<grid, 512, 0, stream>>>(qx, qw, bias, (float*)d_out, M, Dout, Din);
}